// Round 1
// baseline (6396.040 us; speedup 1.0000x reference)
//
#include <hip/hip_runtime.h>
#include <cstdint>
#include <cstddef>

// ---------------------------------------------------------------------------
// StaticGNN fused pipeline, fp32, round 1 (correctness-first).
// N=50000 nodes, E=400000 edges, ND=128, ED=64, HID=128.
// ---------------------------------------------------------------------------

static inline int cdiv(int a, int b) { return (a + b - 1) / b; }

// monotone float<->uint encoding for atomicMax on floats
__device__ __forceinline__ unsigned fenc(float f) {
  unsigned u = __float_as_uint(f);
  return (u & 0x80000000u) ? ~u : (u | 0x80000000u);
}
__device__ __forceinline__ float fdec(unsigned u) {
  return (u & 0x80000000u) ? __uint_as_float(u & 0x7FFFFFFFu) : __uint_as_float(~u);
}

__global__ void init_max_kernel(unsigned* __restrict__ p, int n) {
  int t = blockIdx.x * blockDim.x + threadIdx.x;
  if (t < n) p[t] = 0x007FFFFFu;  // fenc(-inf)
}

// ---------------------------------------------------------------------------
// K1: emb = relu(edge_attr @ epw + epb); atomically scatter into
//     x_out[src] sum, x_in[dst] sum, loop_attr[dst] += edge_attr, counts.
// One wave processes 4 edges; epw (64x128) staged in LDS; edge_attr row held
// one-element-per-lane and broadcast via __shfl.
// ---------------------------------------------------------------------------
__global__ __launch_bounds__(256) void edge_mlp_scatter(
    const float* __restrict__ ea, const int* __restrict__ src,
    const int* __restrict__ dst, const float* __restrict__ epw,
    const float* __restrict__ epb, float* __restrict__ xout,
    float* __restrict__ xin, float* __restrict__ lattr,
    float* __restrict__ cnt_out, float* __restrict__ cnt_in, int E) {
  __shared__ float w[64 * 128];
  __shared__ float bias[128];
  for (int t = threadIdx.x; t < 64 * 128; t += 256) w[t] = epw[t];
  for (int t = threadIdx.x; t < 128; t += 256) bias[t] = epb[t];
  __syncthreads();
  int lane = threadIdx.x & 63, wid = threadIdx.x >> 6;
  long nw = ((long)gridDim.x * 256) >> 6;
  long gw = (long)blockIdx.x * 4 + wid;
  for (long base = gw * 4; base < E; base += nw * 4) {
    long rem = (long)E - base;
    int te = rem < 4 ? (int)rem : 4;
    int s[4], d[4];
    float ear[4];
    for (int e = 0; e < 4; e++) {
      long i = base + ((e < te) ? e : 0);
      s[e] = src[i];
      d[e] = dst[i];
      ear[e] = (e < te) ? ea[i * 64 + lane] : 0.f;
    }
    // loop_attr accumulation (only valid edges)
    for (int e = 0; e < te; e++) atomicAdd(&lattr[(size_t)d[e] * 64 + lane], ear[e]);
    if (lane == 0) {
      for (int e = 0; e < te; e++) {
        atomicAdd(&cnt_out[s[e]], 1.f);
        atomicAdd(&cnt_in[d[e]], 1.f);
      }
    }
    float acc[4][2] = {};
#pragma unroll 8
    for (int k = 0; k < 64; k++) {
      float w0 = w[k * 128 + lane * 2];
      float w1 = w[k * 128 + lane * 2 + 1];
#pragma unroll
      for (int e = 0; e < 4; e++) {
        float aa = __shfl(ear[e], k);
        acc[e][0] += aa * w0;
        acc[e][1] += aa * w1;
      }
    }
    int c = lane * 2;
    for (int e = 0; e < te; e++) {
      float v0 = fmaxf(acc[e][0] + bias[c], 0.f);
      float v1 = fmaxf(acc[e][1] + bias[c + 1], 0.f);
      atomicAdd(&xout[(size_t)s[e] * 128 + c], v0);
      atomicAdd(&xout[(size_t)s[e] * 128 + c + 1], v1);
      atomicAdd(&xin[(size_t)d[e] * 128 + c], v0);
      atomicAdd(&xin[(size_t)d[e] * 128 + c + 1], v1);
    }
  }
}

// K2: divide sums by max(count,1)
__global__ void normalize_means(float* __restrict__ xout, float* __restrict__ xin,
                                float* __restrict__ lattr,
                                const float* __restrict__ co,
                                const float* __restrict__ ci, int N) {
  int t = blockIdx.x * blockDim.x + threadIdx.x;
  if (t >= N * 128) return;
  int n = t >> 7, c = t & 127;
  float rco = 1.f / fmaxf(co[n], 1.f);
  float rci = 1.f / fmaxf(ci[n], 1.f);
  xout[t] *= rco;
  xin[t] *= rci;
  if (c < 64) lattr[(size_t)n * 64 + c] *= rci;
}

// ---------------------------------------------------------------------------
// Generic fp32 GEMM: C[M,Ncols] = A[M,K] @ B[K,Ncols]; A may be a virtual
// concat of up to 3 row-major matrices (for xi = [x_out | x_in | stats]).
// 64x64 block tile, 16 k-chunk, 4x4 micro-tile, 256 threads.
// ---------------------------------------------------------------------------
struct GemmA {
  const float *p0, *p1, *p2;
  int ld0, ld1, ld2;
  int k0, k1;  // k < k0 -> p0 ; k < k1 -> p1 ; else p2
};
__device__ __forceinline__ float loadA(const GemmA& a, int m, int k) {
  if (k < a.k0) return a.p0[(size_t)m * a.ld0 + k];
  if (k < a.k1) return a.p1[(size_t)m * a.ld1 + (k - a.k0)];
  return a.p2[(size_t)m * a.ld2 + (k - a.k1)];
}

__global__ __launch_bounds__(256) void gemm64(GemmA a, const float* __restrict__ B,
                                              int ldb, float* __restrict__ C, int ldc,
                                              int M, int K) {
  __shared__ float As[16][64];
  __shared__ float Bs[16][64];
  int m0 = blockIdx.x * 64, n0 = blockIdx.y * 64;
  int tid = threadIdx.x;
  int tm = tid >> 4, tn = tid & 15;
  float acc[4][4] = {};
  for (int kc = 0; kc < K; kc += 16) {
    {
      int k = tid & 15, mb = tid >> 4;
      int kk = kc + k;
#pragma unroll
      for (int j = 0; j < 4; j++) {
        int m = mb + 16 * j;
        int gm = m0 + m;
        As[k][m] = (kk < K && gm < M) ? loadA(a, gm, kk) : 0.f;
      }
      int n = tid & 63, kb = tid >> 6;
#pragma unroll
      for (int j = 0; j < 4; j++) {
        int k2 = kb * 4 + j;
        int kk2 = kc + k2;
        Bs[k2][n] = (kk2 < K) ? B[(size_t)kk2 * ldb + n0 + n] : 0.f;
      }
    }
    __syncthreads();
#pragma unroll
    for (int k = 0; k < 16; k++) {
      const float* ap = &As[k][tm * 4];
      const float* bp = &Bs[k][tn * 4];
#pragma unroll
      for (int i = 0; i < 4; i++)
#pragma unroll
        for (int j = 0; j < 4; j++) acc[i][j] += ap[i] * bp[j];
    }
    __syncthreads();
  }
#pragma unroll
  for (int i = 0; i < 4; i++) {
    int row = m0 + tm * 4 + i;
    if (row < M) {
      float4 v = make_float4(acc[i][0], acc[i][1], acc[i][2], acc[i][3]);
      *(float4*)&C[(size_t)row * ldc + n0 + tn * 4] = v;
    }
  }
}

// ---------------------------------------------------------------------------
// GATv2 pass A: per extended edge compute e = xl[s]+xr[d]+ea2@we, leaky-relu,
// logit_h = sum_c e*att ; store logit, atomicMax per (d,h).
// One wave / 4 edges; we ([64, H*128]) staged in LDS.
// ---------------------------------------------------------------------------
template <int H>
__global__ __launch_bounds__(256) void attn_logits(
    const float* __restrict__ xl, const float* __restrict__ xr,
    const int* __restrict__ src, const int* __restrict__ dst,
    const float* __restrict__ ea, const float* __restrict__ lattr,
    const float* __restrict__ we, const float* __restrict__ att,
    float* __restrict__ logitbuf, unsigned* __restrict__ maxbuf, int E, int N) {
  constexpr int HC = H * 128;
  constexpr int CPL = HC / 64;
  extern __shared__ float wsh[];  // 64*HC floats (<=64KB)
  for (int t = threadIdx.x; t < 64 * HC; t += 256) wsh[t] = we[t];
  __syncthreads();
  int lane = threadIdx.x & 63, wid = threadIdx.x >> 6;
  float attv[CPL];
#pragma unroll
  for (int j = 0; j < CPL; j++) attv[j] = att[lane * CPL + j];
  long nw = ((long)gridDim.x * 256) >> 6;
  long gw = (long)blockIdx.x * 4 + wid;
  long E2 = (long)E + N;
  for (long base = gw * 4; base < E2; base += nw * 4) {
    long rem = E2 - base;
    int te = rem < 4 ? (int)rem : 4;
    int s[4], d[4];
    float ear[4];
    for (int e = 0; e < 4; e++) {
      long i = base + ((e < te) ? e : 0);
      if (i < E) {
        s[e] = src[i];
        d[e] = dst[i];
        ear[e] = (e < te) ? ea[i * 64 + lane] : 0.f;
      } else {
        int v = (int)(i - E);
        s[e] = v;
        d[e] = v;
        ear[e] = (e < te) ? lattr[(size_t)v * 64 + lane] : 0.f;
      }
    }
    float acc[4][CPL] = {};
#pragma unroll 8
    for (int k = 0; k < 64; k++) {
      float wv[CPL];
#pragma unroll
      for (int j = 0; j < CPL; j++) wv[j] = wsh[k * HC + lane * CPL + j];
#pragma unroll
      for (int e = 0; e < 4; e++) {
        float aa = __shfl(ear[e], k);
#pragma unroll
        for (int j = 0; j < CPL; j++) acc[e][j] += aa * wv[j];
      }
    }
    for (int e = 0; e < te; e++) {
      const float* xlp = &xl[(size_t)s[e] * HC + lane * CPL];
      const float* xrp = &xr[(size_t)d[e] * HC + lane * CPL];
      float ps = 0.f;
#pragma unroll
      for (int j = 0; j < CPL; j++) {
        float ev = acc[e][j] + xlp[j] + xrp[j];
        ev = ev > 0.f ? ev : 0.2f * ev;
        ps += ev * attv[j];
      }
      long i = base + e;
      if (H == 2) {
        float h0 = (lane < 32) ? ps : 0.f;
        float h1 = (lane < 32) ? 0.f : ps;
#pragma unroll
        for (int m = 1; m < 64; m <<= 1) {
          h0 += __shfl_xor(h0, m);
          h1 += __shfl_xor(h1, m);
        }
        if (lane == 0) {
          logitbuf[i * 2] = h0;
          logitbuf[i * 2 + 1] = h1;
          atomicMax(&maxbuf[d[e] * 2], fenc(h0));
          atomicMax(&maxbuf[d[e] * 2 + 1], fenc(h1));
        }
      } else {
        float h0 = ps;
#pragma unroll
        for (int m = 1; m < 64; m <<= 1) h0 += __shfl_xor(h0, m);
        if (lane == 0) {
          logitbuf[i] = h0;
          atomicMax(&maxbuf[d[e]], fenc(h0));
        }
      }
    }
  }
}

// pass B: a = exp(logit - max[d]); denom[d] += a (in place over logitbuf)
template <int H>
__global__ void attn_norm(float* __restrict__ logitbuf,
                          const unsigned* __restrict__ maxbuf,
                          float* __restrict__ denom, const int* __restrict__ dst,
                          int E, int N) {
  long E2 = (long)E + N;
  long total = E2 * H;
  for (long t = (long)blockIdx.x * blockDim.x + threadIdx.x; t < total;
       t += (long)gridDim.x * blockDim.x) {
    long i = (H == 2) ? (t >> 1) : t;
    int h = (H == 2) ? (int)(t & 1) : 0;
    int d = (i < E) ? dst[i] : (int)(i - E);
    float m = fdec(maxbuf[d * H + h]);
    float a = expf(logitbuf[t] - m);
    logitbuf[t] = a;
    atomicAdd(&denom[d * H + h], a);
  }
}

// pass C: agg[d] += xl[s] * a/denom[d]
template <int H>
__global__ void attn_agg(const float* __restrict__ xl, const float* __restrict__ aw,
                         const float* __restrict__ denom, const int* __restrict__ src,
                         const int* __restrict__ dst, float* __restrict__ agg, int E,
                         int N) {
  constexpr int HC = H * 128;
  constexpr int Qg = HC / 4;
  long E2 = (long)E + N;
  long total = E2 * Qg;
  for (long t = (long)blockIdx.x * blockDim.x + threadIdx.x; t < total;
       t += (long)gridDim.x * blockDim.x) {
    long i = t / Qg;
    int q = (int)(t - i * Qg);
    int c = q * 4;
    int h = c >> 7;
    int s, d;
    if (i < E) {
      s = src[i];
      d = dst[i];
    } else {
      s = d = (int)(i - E);
    }
    float a = aw[i * H + h] / fmaxf(denom[d * H + h], 1e-16f);
    float4 x = *(const float4*)&xl[(size_t)s * HC + c];
    float* g = &agg[(size_t)d * HC + c];
    atomicAdd(g, x.x * a);
    atomicAdd(g + 1, x.y * a);
    atomicAdd(g + 2, x.z * a);
    atomicAdd(g + 3, x.w * a);
  }
}

// pass D: out = elu(layer_norm(mean_heads(agg) + bias) * g + b)
template <int H>
__global__ __launch_bounds__(256) void post_ln(const float* __restrict__ agg,
                                               const float* __restrict__ bias,
                                               const float* __restrict__ gam,
                                               const float* __restrict__ bet,
                                               float* __restrict__ out, int N) {
  int lane = threadIdx.x & 63, wid = threadIdx.x >> 6;
  int n = blockIdx.x * 4 + wid;
  if (n >= N) return;
  int c = lane * 2;
  float v0, v1;
  if (H == 2) {
    v0 = (agg[(size_t)n * 256 + c] + agg[(size_t)n * 256 + 128 + c]) * 0.5f;
    v1 = (agg[(size_t)n * 256 + c + 1] + agg[(size_t)n * 256 + 129 + c]) * 0.5f;
  } else {
    v0 = agg[(size_t)n * 128 + c];
    v1 = agg[(size_t)n * 128 + c + 1];
  }
  v0 += bias[c];
  v1 += bias[c + 1];
  float s = v0 + v1;
#pragma unroll
  for (int m = 1; m < 64; m <<= 1) s += __shfl_xor(s, m);
  float mu = s * (1.f / 128.f);
  float d0 = v0 - mu, d1 = v1 - mu;
  float vs = d0 * d0 + d1 * d1;
#pragma unroll
  for (int m = 1; m < 64; m <<= 1) vs += __shfl_xor(vs, m);
  float rstd = rsqrtf(vs * (1.f / 128.f) + 1e-5f);
  float y0 = d0 * rstd * gam[c] + bet[c];
  float y1 = d1 * rstd * gam[c + 1] + bet[c + 1];
  out[(size_t)n * 128 + c] = y0 > 0.f ? y0 : expm1f(y0);
  out[(size_t)n * 128 + c + 1] = y1 > 0.f ? y1 : expm1f(y1);
}

// ---------------------------------------------------------------------------
// Classifier: t1 = relu(P[s]+Q[d]+ea@Wc+c1b); t2 = relu(t1@c2w+c2b);
// out = t2.c3w + c3b.  Wc=c1w[256:320], c2w staged in LDS (exactly 64KB).
// ---------------------------------------------------------------------------
__global__ __launch_bounds__(256) void classifier(
    const float* __restrict__ P, const float* __restrict__ Q,
    const int* __restrict__ src, const int* __restrict__ dst,
    const float* __restrict__ ea, const float* __restrict__ c1w_c,
    const float* __restrict__ c1b, const float* __restrict__ c2w,
    const float* __restrict__ c2b, const float* __restrict__ c3w,
    const float* __restrict__ c3b, float* __restrict__ out, int E) {
  __shared__ float wc[64 * 128];
  __shared__ float w2[128 * 64];
  for (int t = threadIdx.x; t < 64 * 128; t += 256) wc[t] = c1w_c[t];
  for (int t = threadIdx.x; t < 128 * 64; t += 256) w2[t] = c2w[t];
  __syncthreads();
  int lane = threadIdx.x & 63, wid = threadIdx.x >> 6;
  float cb = c3b[0];
  float w3l = c3w[lane];
  float b2l = c2b[lane];
  int c = lane * 2;
  float b1a = c1b[c], b1b = c1b[c + 1];
  long nw = ((long)gridDim.x * 256) >> 6;
  long gw = (long)blockIdx.x * 4 + wid;
  for (long base = gw * 4; base < E; base += nw * 4) {
    long rem = (long)E - base;
    int te = rem < 4 ? (int)rem : 4;
    int s[4], d[4];
    float ear[4];
    for (int e = 0; e < 4; e++) {
      long i = base + ((e < te) ? e : 0);
      s[e] = src[i];
      d[e] = dst[i];
      ear[e] = (e < te) ? ea[i * 64 + lane] : 0.f;
    }
    float acc[4][2] = {};
#pragma unroll 8
    for (int k = 0; k < 64; k++) {
      float w0 = wc[k * 128 + c];
      float w1 = wc[k * 128 + c + 1];
#pragma unroll
      for (int e = 0; e < 4; e++) {
        float aa = __shfl(ear[e], k);
        acc[e][0] += aa * w0;
        acc[e][1] += aa * w1;
      }
    }
    float t1r[4][2];
#pragma unroll
    for (int e = 0; e < 4; e++) {
      float p0 = P[(size_t)s[e] * 128 + c], p1 = P[(size_t)s[e] * 128 + c + 1];
      float q0 = Q[(size_t)d[e] * 128 + c], q1 = Q[(size_t)d[e] * 128 + c + 1];
      t1r[e][0] = fmaxf(acc[e][0] + p0 + q0 + b1a, 0.f);
      t1r[e][1] = fmaxf(acc[e][1] + p1 + q1 + b1b, 0.f);
    }
    float t2r[4] = {};
#pragma unroll 4
    for (int k2 = 0; k2 < 64; k2++) {
      float wa = w2[(2 * k2) * 64 + lane];
      float wb = w2[(2 * k2 + 1) * 64 + lane];
#pragma unroll
      for (int e = 0; e < 4; e++)
        t2r[e] += __shfl(t1r[e][0], k2) * wa + __shfl(t1r[e][1], k2) * wb;
    }
    float v[4];
#pragma unroll
    for (int e = 0; e < 4; e++) {
      float t2 = fmaxf(t2r[e] + b2l, 0.f);
      v[e] = t2 * w3l;
    }
#pragma unroll
    for (int m = 1; m < 64; m <<= 1) {
      v[0] += __shfl_xor(v[0], m);
      v[1] += __shfl_xor(v[1], m);
      v[2] += __shfl_xor(v[2], m);
      v[3] += __shfl_xor(v[3], m);
    }
    if (lane == 0)
      for (int e = 0; e < te; e++) out[base + e] = v[e] + cb;
  }
}

// ---------------------------------------------------------------------------
extern "C" void kernel_launch(void* const* d_in, const int* in_sizes, int n_in,
                              void* d_out, int out_size, void* d_ws, size_t ws_size,
                              hipStream_t stream) {
  const int N = in_sizes[1] / 2;   // node_stats [N,2]
  const int E = in_sizes[3] / 64;  // edge_attr [E,64]

  const float* node_stats = (const float*)d_in[1];
  const int* src = (const int*)d_in[2];
  const int* dst = (const int*)d_in[2] + E;
  const float* edge_attr = (const float*)d_in[3];
  const float* epw = (const float*)d_in[4];
  const float* epb = (const float*)d_in[5];
  const float* g1wl = (const float*)d_in[6];
  const float* g1wr = (const float*)d_in[7];
  const float* g1we = (const float*)d_in[8];
  const float* g1att = (const float*)d_in[9];
  const float* g1b = (const float*)d_in[10];
  const float* n1g = (const float*)d_in[11];
  const float* n1b = (const float*)d_in[12];
  const float* g2wl = (const float*)d_in[13];
  const float* g2wr = (const float*)d_in[14];
  const float* g2we = (const float*)d_in[15];
  const float* g2att = (const float*)d_in[16];
  const float* g2b = (const float*)d_in[17];
  const float* n2g = (const float*)d_in[18];
  const float* n2b = (const float*)d_in[19];
  const float* c1w = (const float*)d_in[20];
  const float* c1b = (const float*)d_in[21];
  const float* c2w = (const float*)d_in[22];
  const float* c2b = (const float*)d_in[23];
  const float* c3w = (const float*)d_in[24];
  const float* c3b = (const float*)d_in[25];
  float* out = (float*)d_out;

  // workspace arena (floats)
  float* w = (float*)d_ws;
  size_t o = 0;
  auto alloc = [&](size_t n) { float* p = w + o; o += n; return p; };
  float* xout = alloc((size_t)N * 128);   // later: xl2, then P
  float* xin = alloc((size_t)N * 128);    // later: xr2, then Q
  float* lattr = alloc((size_t)N * 64);   // loop_attr (both layers)
  float* cnto = alloc(N);
  float* cnti = alloc(N);
  float* xl1 = alloc((size_t)N * 256);    // later: h2
  float* xr1 = alloc((size_t)N * 256);    // later: agg (both layers)
  float* lg = alloc((size_t)(E + N) * 2); // logits / attention weights
  unsigned* mx = (unsigned*)alloc((size_t)N * 2);
  float* dn = alloc((size_t)N * 2);
  float* h1 = alloc((size_t)N * 128);
  float* xl2 = xout;
  float* xr2 = xin;
  float* agg = xr1;
  float* h2 = xl1;
  float* P = xout;
  float* Q = xin;

  // ---- stage 0: zero accumulators (xout..cnti are contiguous) ----
  hipMemsetAsync(xout, 0, (size_t)N * 322 * sizeof(float), stream);

  // ---- stage 1: edge MLP + seg-mean scatter ----
  edge_mlp_scatter<<<1024, 256, 0, stream>>>(edge_attr, src, dst, epw, epb, xout,
                                             xin, lattr, cnto, cnti, E);
  normalize_means<<<cdiv(N * 128, 256), 256, 0, stream>>>(xout, xin, lattr, cnto,
                                                          cnti, N);

  // ---- stage 2: xl1/xr1 = xi @ g1wl / g1wr  (xi = [xout|xin|stats], K=258) ----
  GemmA axi{xout, xin, node_stats, 128, 128, 2, 128, 256};
  {
    dim3 g(cdiv(N, 64), 4);
    gemm64<<<g, 256, 0, stream>>>(axi, g1wl, 256, xl1, 256, N, 258);
    gemm64<<<g, 256, 0, stream>>>(axi, g1wr, 256, xr1, 256, N, 258);
  }

  // ---- stage 3: GATv2 layer 1 (H=2) ----
  init_max_kernel<<<cdiv(N * 2, 256), 256, 0, stream>>>(mx, N * 2);
  attn_logits<2><<<512, 256, 64 * 256 * sizeof(float), stream>>>(
      xl1, xr1, src, dst, edge_attr, lattr, g1we, g1att, lg, mx, E, N);
  hipMemsetAsync(dn, 0, (size_t)N * 2 * sizeof(float), stream);
  hipMemsetAsync(agg, 0, (size_t)N * 256 * sizeof(float), stream);
  attn_norm<2><<<2048, 256, 0, stream>>>(lg, mx, dn, dst, E, N);
  attn_agg<2><<<8192, 256, 0, stream>>>(xl1, lg, dn, src, dst, agg, E, N);
  post_ln<2><<<cdiv(N, 4), 256, 0, stream>>>(agg, g1b, n1g, n1b, h1, N);

  // ---- stage 4: xl2/xr2 = h1 @ g2wl / g2wr ----
  GemmA ah1{h1, nullptr, nullptr, 128, 0, 0, 128, 128};
  {
    dim3 g(cdiv(N, 64), 2);
    gemm64<<<g, 256, 0, stream>>>(ah1, g2wl, 128, xl2, 128, N, 128);
    gemm64<<<g, 256, 0, stream>>>(ah1, g2wr, 128, xr2, 128, N, 128);
  }

  // ---- stage 5: GATv2 layer 2 (H=1) ----
  init_max_kernel<<<cdiv(N * 2, 256), 256, 0, stream>>>(mx, N * 2);
  attn_logits<1><<<512, 256, 64 * 128 * sizeof(float), stream>>>(
      xl2, xr2, src, dst, edge_attr, lattr, g2we, g2att, lg, mx, E, N);
  hipMemsetAsync(dn, 0, (size_t)N * 2 * sizeof(float), stream);
  hipMemsetAsync(agg, 0, (size_t)N * 128 * sizeof(float), stream);
  attn_norm<1><<<2048, 256, 0, stream>>>(lg, mx, dn, dst, E, N);
  attn_agg<1><<<4096, 256, 0, stream>>>(xl2, lg, dn, src, dst, agg, E, N);
  post_ln<1><<<cdiv(N, 4), 256, 0, stream>>>(agg, g2b, n2g, n2b, h2, N);

  // ---- stage 6: classifier ----
  GemmA ah2{h2, nullptr, nullptr, 128, 0, 0, 128, 128};
  {
    dim3 g(cdiv(N, 64), 2);
    gemm64<<<g, 256, 0, stream>>>(ah2, c1w, 128, P, 128, N, 128);            // Wa
    gemm64<<<g, 256, 0, stream>>>(ah2, c1w + 128 * 128, 128, Q, 128, N, 128);  // Wb
  }
  classifier<<<512, 256, 0, stream>>>(P, Q, src, dst, edge_attr, c1w + 256 * 128,
                                      c1b, c2w, c2b, c3w, c3b, out, E);
}

// Round 2
// 4226.123 us; speedup vs baseline: 1.5135x; 1.5135x over previous
//
#include <hip/hip_runtime.h>
#include <cstdint>
#include <cstddef>

// ---------------------------------------------------------------------------
// StaticGNN fused pipeline, fp32, round 2: CSR gather (no float atomics).
// N=50000 nodes, E=400000 edges, ND=128, ED=64, HID=128.
// ---------------------------------------------------------------------------

static inline int cdiv(int a, int b) { return (a + b - 1) / b; }

// ---------------------------------------------------------------------------
// CSR build: degree count (int atomics), block scan, slot scatter.
// ---------------------------------------------------------------------------
__global__ void count_deg(const int* __restrict__ src, const int* __restrict__ dst,
                          int* __restrict__ dsrc, int* __restrict__ ddst, int E) {
  int t = blockIdx.x * blockDim.x + threadIdx.x;
  if (t < E) {
    atomicAdd(&dsrc[src[t]], 1);
    atomicAdd(&ddst[dst[t]], 1);
  }
}

// single block, 1024 threads: exclusive scan of two degree arrays
__global__ __launch_bounds__(1024) void scan_pair(
    const int* __restrict__ degA, const int* __restrict__ degB,
    int* __restrict__ rowA, int* __restrict__ rowB, int* __restrict__ curA,
    int* __restrict__ curB, int N) {
  __shared__ int part[1024];
  int tid = threadIdx.x;
  int chunk = (N + 1023) / 1024;
  for (int arr = 0; arr < 2; arr++) {
    const int* deg = arr ? degB : degA;
    int* row = arr ? rowB : rowA;
    int* cur = arr ? curB : curA;
    int lo = tid * chunk, hi = min(lo + chunk, N);
    int s = 0;
    for (int i = lo; i < hi; i++) s += deg[i];
    part[tid] = s;
    __syncthreads();
    for (int off = 1; off < 1024; off <<= 1) {
      int v = (tid >= off) ? part[tid - off] : 0;
      __syncthreads();
      if (tid >= off) part[tid] += v;
      __syncthreads();
    }
    int run = (tid == 0) ? 0 : part[tid - 1];
    for (int i = lo; i < hi; i++) {
      row[i] = run;
      cur[i] = run;
      run += deg[i];
    }
    if (tid == 1023) row[N] = part[1023];
    __syncthreads();
  }
}

__global__ void scatter_eid(const int* __restrict__ src, const int* __restrict__ dst,
                            int* __restrict__ csrc, int* __restrict__ cdst,
                            int* __restrict__ esrc, int* __restrict__ edst, int E) {
  int t = blockIdx.x * blockDim.x + threadIdx.x;
  if (t < E) {
    int p = atomicAdd(&csrc[src[t]], 1);
    esrc[p] = t;
    int q = atomicAdd(&cdst[dst[t]], 1);
    edst[q] = t;
  }
}

// ---------------------------------------------------------------------------
// seg-mean of relu(ea@epw+epb) over incident edges (gather). Wave per node.
// Optionally also produces lattr = mean of raw edge_attr (dst side).
// ---------------------------------------------------------------------------
__global__ __launch_bounds__(256) void seg_mean_mlp(
    const int* __restrict__ row, const int* __restrict__ eid,
    const float* __restrict__ ea, const float* __restrict__ epw,
    const float* __restrict__ epb, float* __restrict__ outm,
    float* __restrict__ lattr, int N) {
  __shared__ float w[64 * 128];
  __shared__ float b[128];
  for (int t = threadIdx.x; t < 64 * 128; t += 256) w[t] = epw[t];
  for (int t = threadIdx.x; t < 128; t += 256) b[t] = epb[t];
  __syncthreads();
  int lane = threadIdx.x & 63, wid = threadIdx.x >> 6;
  int n = blockIdx.x * 4 + wid;
  if (n >= N) return;
  int lo = row[n], hi = row[n + 1];
  int deg = hi - lo;
  int c = lane * 2;
  float acc0 = 0.f, acc1 = 0.f, la = 0.f;
  float ba = b[c], bb = b[c + 1];
  for (int j = lo; j < hi; j += 4) {
    int te = min(4, hi - j);
    float v[4];
#pragma unroll
    for (int q = 0; q < 4; q++) {
      int e = eid[min(j + q, hi - 1)];
      v[q] = (q < te) ? ea[(size_t)e * 64 + lane] : 0.f;
    }
    float m0[4] = {}, m1[4] = {};
#pragma unroll 8
    for (int k = 0; k < 64; k++) {
      float w0 = w[k * 128 + c];
      float w1 = w[k * 128 + c + 1];
#pragma unroll
      for (int q = 0; q < 4; q++) {
        float a = __shfl(v[q], k);
        m0[q] += a * w0;
        m1[q] += a * w1;
      }
    }
    for (int q = 0; q < te; q++) {
      la += v[q];
      acc0 += fmaxf(m0[q] + ba, 0.f);
      acc1 += fmaxf(m1[q] + bb, 0.f);
    }
  }
  float r = 1.f / fmaxf((float)deg, 1.f);
  outm[(size_t)n * 128 + c] = acc0 * r;
  outm[(size_t)n * 128 + c + 1] = acc1 * r;
  if (lattr) lattr[(size_t)n * 64 + lane] = la * r;
}

// ---------------------------------------------------------------------------
// Generic fp32 GEMM: C[M,Ncols] = A[M,K] @ B[K,Ncols]; A may be a virtual
// concat of up to 3 row-major matrices (for xi = [x_out | x_in | stats]).
// ---------------------------------------------------------------------------
struct GemmA {
  const float *p0, *p1, *p2;
  int ld0, ld1, ld2;
  int k0, k1;
};
__device__ __forceinline__ float loadA(const GemmA& a, int m, int k) {
  if (k < a.k0) return a.p0[(size_t)m * a.ld0 + k];
  if (k < a.k1) return a.p1[(size_t)m * a.ld1 + (k - a.k0)];
  return a.p2[(size_t)m * a.ld2 + (k - a.k1)];
}

__global__ __launch_bounds__(256) void gemm64(GemmA a, const float* __restrict__ B,
                                              int ldb, float* __restrict__ C, int ldc,
                                              int M, int K) {
  __shared__ float As[16][64];
  __shared__ float Bs[16][64];
  int m0 = blockIdx.x * 64, n0 = blockIdx.y * 64;
  int tid = threadIdx.x;
  int tm = tid >> 4, tn = tid & 15;
  float acc[4][4] = {};
  for (int kc = 0; kc < K; kc += 16) {
    {
      int k = tid & 15, mb = tid >> 4;
      int kk = kc + k;
#pragma unroll
      for (int j = 0; j < 4; j++) {
        int m = mb + 16 * j;
        int gm = m0 + m;
        As[k][m] = (kk < K && gm < M) ? loadA(a, gm, kk) : 0.f;
      }
      int n = tid & 63, kb = tid >> 6;
#pragma unroll
      for (int j = 0; j < 4; j++) {
        int k2 = kb * 4 + j;
        int kk2 = kc + k2;
        Bs[k2][n] = (kk2 < K) ? B[(size_t)kk2 * ldb + n0 + n] : 0.f;
      }
    }
    __syncthreads();
#pragma unroll
    for (int k = 0; k < 16; k++) {
      const float* ap = &As[k][tm * 4];
      const float* bp = &Bs[k][tn * 4];
#pragma unroll
      for (int i = 0; i < 4; i++)
#pragma unroll
        for (int j = 0; j < 4; j++) acc[i][j] += ap[i] * bp[j];
    }
    __syncthreads();
  }
#pragma unroll
  for (int i = 0; i < 4; i++) {
    int row = m0 + tm * 4 + i;
    if (row < M) {
      float4 v = make_float4(acc[i][0], acc[i][1], acc[i][2], acc[i][3]);
      *(float4*)&C[(size_t)row * ldc + n0 + tn * 4] = v;
    }
  }
}

// ---------------------------------------------------------------------------
// GATv2 pass A: per extended edge, e = xl[s]+xr[d]+ea2@we, leaky-relu,
// logit_h = sum_c e*att ; store logit. Wave per 4 edges; we staged in LDS.
// ---------------------------------------------------------------------------
template <int H>
__global__ __launch_bounds__(256) void attn_logits(
    const float* __restrict__ xl, const float* __restrict__ xr,
    const int* __restrict__ src, const int* __restrict__ dst,
    const float* __restrict__ ea, const float* __restrict__ lattr,
    const float* __restrict__ we, const float* __restrict__ att,
    float* __restrict__ logitbuf, int E, int N) {
  constexpr int HC = H * 128;
  constexpr int CPL = HC / 64;
  extern __shared__ float wsh[];
  for (int t = threadIdx.x; t < 64 * HC; t += 256) wsh[t] = we[t];
  __syncthreads();
  int lane = threadIdx.x & 63, wid = threadIdx.x >> 6;
  float attv[CPL];
#pragma unroll
  for (int j = 0; j < CPL; j++) attv[j] = att[lane * CPL + j];
  long nw = ((long)gridDim.x * 256) >> 6;
  long gw = (long)blockIdx.x * 4 + wid;
  long E2 = (long)E + N;
  for (long base = gw * 4; base < E2; base += nw * 4) {
    long rem = E2 - base;
    int te = rem < 4 ? (int)rem : 4;
    int s[4], d[4];
    float ear[4];
    for (int e = 0; e < 4; e++) {
      long i = base + ((e < te) ? e : 0);
      if (i < E) {
        s[e] = src[i];
        d[e] = dst[i];
        ear[e] = (e < te) ? ea[i * 64 + lane] : 0.f;
      } else {
        int v = (int)(i - E);
        s[e] = v;
        d[e] = v;
        ear[e] = (e < te) ? lattr[(size_t)v * 64 + lane] : 0.f;
      }
    }
    float acc[4][CPL] = {};
#pragma unroll 8
    for (int k = 0; k < 64; k++) {
      float wv[CPL];
#pragma unroll
      for (int j = 0; j < CPL; j++) wv[j] = wsh[k * HC + lane * CPL + j];
#pragma unroll
      for (int e = 0; e < 4; e++) {
        float aa = __shfl(ear[e], k);
#pragma unroll
        for (int j = 0; j < CPL; j++) acc[e][j] += aa * wv[j];
      }
    }
    for (int e = 0; e < te; e++) {
      const float* xlp = &xl[(size_t)s[e] * HC + lane * CPL];
      const float* xrp = &xr[(size_t)d[e] * HC + lane * CPL];
      float ps = 0.f;
#pragma unroll
      for (int j = 0; j < CPL; j++) {
        float ev = acc[e][j] + xlp[j] + xrp[j];
        ev = ev > 0.f ? ev : 0.2f * ev;
        ps += ev * attv[j];
      }
      long i = base + e;
      if (H == 2) {
        float h0 = (lane < 32) ? ps : 0.f;
        float h1 = (lane < 32) ? 0.f : ps;
#pragma unroll
        for (int m = 1; m < 64; m <<= 1) {
          h0 += __shfl_xor(h0, m);
          h1 += __shfl_xor(h1, m);
        }
        if (lane == 0) {
          logitbuf[i * 2] = h0;
          logitbuf[i * 2 + 1] = h1;
        }
      } else {
        float h0 = ps;
#pragma unroll
        for (int m = 1; m < 64; m <<= 1) h0 += __shfl_xor(h0, m);
        if (lane == 0) logitbuf[i] = h0;
      }
    }
  }
}

// ---------------------------------------------------------------------------
// Fused softmax + aggregate + head-mean + bias + LayerNorm + ELU.
// Wave per destination node, CSR gather over in-edges + self-loop.
// ---------------------------------------------------------------------------
template <int H>
__global__ __launch_bounds__(256) void attn_fused(
    const float* __restrict__ xl, const float* __restrict__ lg,
    const int* __restrict__ row, const int* __restrict__ eid,
    const int* __restrict__ src, const float* __restrict__ bias,
    const float* __restrict__ gam, const float* __restrict__ bet,
    float* __restrict__ hout, int E, int N) {
  constexpr int HC = H * 128;
  constexpr int CPL = HC / 64;
  int lane = threadIdx.x & 63, wid = threadIdx.x >> 6;
  int n = blockIdx.x * 4 + wid;
  if (n >= N) return;
  int lo = row[n], hi = row[n + 1];
  int myh = (H == 2) ? (lane >> 5) : 0;
  // pass 1: max logit over self-loop + in-edges (broadcast loads)
  float m = lg[(size_t)(E + n) * H + myh];
  for (int j = lo; j < hi; j++) m = fmaxf(m, lg[(size_t)eid[j] * H + myh]);
  // pass 2: exp-weighted accumulate
  float asum = 0.f;
  float acc[CPL] = {};
  {
    float a = __expf(lg[(size_t)(E + n) * H + myh] - m);
    asum += a;
    const float* xp = &xl[(size_t)n * HC + lane * CPL];
#pragma unroll
    for (int k = 0; k < CPL; k++) acc[k] += a * xp[k];
  }
  for (int j = lo; j < hi; j++) {
    int e = eid[j];
    int s = src[e];
    float a = __expf(lg[(size_t)e * H + myh] - m);
    asum += a;
    const float* xp = &xl[(size_t)s * HC + lane * CPL];
#pragma unroll
    for (int k = 0; k < CPL; k++) acc[k] += a * xp[k];
  }
  float inv = 1.f / fmaxf(asum, 1e-16f);
#pragma unroll
  for (int k = 0; k < CPL; k++) acc[k] *= inv;
  // head mean (H=2: pair lane l with l^32), bias, LN, elu
  int ch;
  if (H == 2) {
#pragma unroll
    for (int k = 0; k < CPL; k++)
      acc[k] = (acc[k] + __shfl_xor(acc[k], 32)) * 0.5f;
    ch = (lane & 31) * CPL;
  } else {
    ch = lane * CPL;
  }
#pragma unroll
  for (int k = 0; k < CPL; k++) acc[k] += bias[ch + k];
  float s = 0.f;
#pragma unroll
  for (int k = 0; k < CPL; k++) s += acc[k];
#pragma unroll
  for (int mm = 1; mm < 64; mm <<= 1) s += __shfl_xor(s, mm);
  constexpr float dupn = (H == 2) ? 256.f : 128.f;
  float mu = s / dupn;
  float vs = 0.f;
#pragma unroll
  for (int k = 0; k < CPL; k++) {
    acc[k] -= mu;
    vs += acc[k] * acc[k];
  }
#pragma unroll
  for (int mm = 1; mm < 64; mm <<= 1) vs += __shfl_xor(vs, mm);
  float rstd = rsqrtf(vs / dupn + 1e-5f);
  float y[CPL];
#pragma unroll
  for (int k = 0; k < CPL; k++) {
    float v = acc[k] * rstd * gam[ch + k] + bet[ch + k];
    y[k] = v > 0.f ? v : expm1f(v);
  }
  if (H == 2) {
    if (lane < 32) {
      float4 o = make_float4(y[0], y[1], y[2], y[3]);
      *(float4*)&hout[(size_t)n * 128 + ch] = o;
    }
  } else {
    float2 o = make_float2(y[0], y[1]);
    *(float2*)&hout[(size_t)n * 128 + ch] = o;
  }
}

// ---------------------------------------------------------------------------
// Classifier: t1 = relu(P[s]+Q[d]+ea@Wc+c1b); t2 = relu(t1@c2w+c2b);
// out = t2.c3w + c3b.
// ---------------------------------------------------------------------------
__global__ __launch_bounds__(256) void classifier(
    const float* __restrict__ P, const float* __restrict__ Q,
    const int* __restrict__ src, const int* __restrict__ dst,
    const float* __restrict__ ea, const float* __restrict__ c1w_c,
    const float* __restrict__ c1b, const float* __restrict__ c2w,
    const float* __restrict__ c2b, const float* __restrict__ c3w,
    const float* __restrict__ c3b, float* __restrict__ out, int E) {
  __shared__ float wc[64 * 128];
  __shared__ float w2[128 * 64];
  for (int t = threadIdx.x; t < 64 * 128; t += 256) wc[t] = c1w_c[t];
  for (int t = threadIdx.x; t < 128 * 64; t += 256) w2[t] = c2w[t];
  __syncthreads();
  int lane = threadIdx.x & 63, wid = threadIdx.x >> 6;
  float cb = c3b[0];
  float w3l = c3w[lane];
  float b2l = c2b[lane];
  int c = lane * 2;
  float b1a = c1b[c], b1b = c1b[c + 1];
  long nw = ((long)gridDim.x * 256) >> 6;
  long gw = (long)blockIdx.x * 4 + wid;
  for (long base = gw * 4; base < E; base += nw * 4) {
    long rem = (long)E - base;
    int te = rem < 4 ? (int)rem : 4;
    int s[4], d[4];
    float ear[4];
    for (int e = 0; e < 4; e++) {
      long i = base + ((e < te) ? e : 0);
      s[e] = src[i];
      d[e] = dst[i];
      ear[e] = (e < te) ? ea[i * 64 + lane] : 0.f;
    }
    float acc[4][2] = {};
#pragma unroll 8
    for (int k = 0; k < 64; k++) {
      float w0 = wc[k * 128 + c];
      float w1 = wc[k * 128 + c + 1];
#pragma unroll
      for (int e = 0; e < 4; e++) {
        float aa = __shfl(ear[e], k);
        acc[e][0] += aa * w0;
        acc[e][1] += aa * w1;
      }
    }
    float t1r[4][2];
#pragma unroll
    for (int e = 0; e < 4; e++) {
      float p0 = P[(size_t)s[e] * 128 + c], p1 = P[(size_t)s[e] * 128 + c + 1];
      float q0 = Q[(size_t)d[e] * 128 + c], q1 = Q[(size_t)d[e] * 128 + c + 1];
      t1r[e][0] = fmaxf(acc[e][0] + p0 + q0 + b1a, 0.f);
      t1r[e][1] = fmaxf(acc[e][1] + p1 + q1 + b1b, 0.f);
    }
    float t2r[4] = {};
#pragma unroll 4
    for (int k2 = 0; k2 < 64; k2++) {
      float wa = w2[(2 * k2) * 64 + lane];
      float wb = w2[(2 * k2 + 1) * 64 + lane];
#pragma unroll
      for (int e = 0; e < 4; e++)
        t2r[e] += __shfl(t1r[e][0], k2) * wa + __shfl(t1r[e][1], k2) * wb;
    }
    float v[4];
#pragma unroll
    for (int e = 0; e < 4; e++) {
      float t2 = fmaxf(t2r[e] + b2l, 0.f);
      v[e] = t2 * w3l;
    }
#pragma unroll
    for (int m = 1; m < 64; m <<= 1) {
      v[0] += __shfl_xor(v[0], m);
      v[1] += __shfl_xor(v[1], m);
      v[2] += __shfl_xor(v[2], m);
      v[3] += __shfl_xor(v[3], m);
    }
    if (lane == 0)
      for (int e = 0; e < te; e++) out[base + e] = v[e] + cb;
  }
}

// ---------------------------------------------------------------------------
extern "C" void kernel_launch(void* const* d_in, const int* in_sizes, int n_in,
                              void* d_out, int out_size, void* d_ws, size_t ws_size,
                              hipStream_t stream) {
  const int N = in_sizes[1] / 2;   // node_stats [N,2]
  const int E = in_sizes[3] / 64;  // edge_attr [E,64]

  const float* node_stats = (const float*)d_in[1];
  const int* src = (const int*)d_in[2];
  const int* dst = (const int*)d_in[2] + E;
  const float* edge_attr = (const float*)d_in[3];
  const float* epw = (const float*)d_in[4];
  const float* epb = (const float*)d_in[5];
  const float* g1wl = (const float*)d_in[6];
  const float* g1wr = (const float*)d_in[7];
  const float* g1we = (const float*)d_in[8];
  const float* g1att = (const float*)d_in[9];
  const float* g1b = (const float*)d_in[10];
  const float* n1g = (const float*)d_in[11];
  const float* n1b = (const float*)d_in[12];
  const float* g2wl = (const float*)d_in[13];
  const float* g2wr = (const float*)d_in[14];
  const float* g2we = (const float*)d_in[15];
  const float* g2att = (const float*)d_in[16];
  const float* g2b = (const float*)d_in[17];
  const float* n2g = (const float*)d_in[18];
  const float* n2b = (const float*)d_in[19];
  const float* c1w = (const float*)d_in[20];
  const float* c1b = (const float*)d_in[21];
  const float* c2w = (const float*)d_in[22];
  const float* c2b = (const float*)d_in[23];
  const float* c3w = (const float*)d_in[24];
  const float* c3b = (const float*)d_in[25];
  float* out = (float*)d_out;

  // workspace arena
  float* w = (float*)d_ws;
  size_t o = 0;
  auto alloc = [&](size_t n) { float* p = w + o; o += n; return p; };
  float* xout = alloc((size_t)N * 128);    // later: xl2, then P
  float* xin = alloc((size_t)N * 128);     // later: xr2, then Q
  float* lattr = alloc((size_t)N * 64);    // loop_attr
  float* xl1 = alloc((size_t)N * 256);     // later: h2
  float* xr1 = alloc((size_t)N * 256);     // later: h1 (free after attn_logits<2>)
  float* lg = alloc((size_t)(E + N) * 2);  // logits
  int* row_src = (int*)alloc((size_t)(N + 1));
  int* row_dst = (int*)alloc((size_t)(N + 1));
  int* deg_src = (int*)alloc((size_t)N);   // deg_src + deg_dst contiguous (memset)
  int* deg_dst = (int*)alloc((size_t)N);
  int* cur_src = (int*)alloc((size_t)N);
  int* cur_dst = (int*)alloc((size_t)N);
  int* eid_src = (int*)alloc((size_t)E);
  int* eid_dst = (int*)alloc((size_t)E);
  float* h1 = xr1;   // alias: xr1 dead after attn_logits<2>
  float* xl2 = xout;
  float* xr2 = xin;
  float* h2 = xl1;   // alias: xl1 dead after attn_fused<2>
  float* P = xout;
  float* Q = xin;

  // ---- stage 0: build CSR (src and dst) ----
  hipMemsetAsync(deg_src, 0, (size_t)2 * N * sizeof(int), stream);
  count_deg<<<cdiv(E, 256), 256, 0, stream>>>(src, dst, deg_src, deg_dst, E);
  scan_pair<<<1, 1024, 0, stream>>>(deg_src, deg_dst, row_src, row_dst, cur_src,
                                    cur_dst, N);
  scatter_eid<<<cdiv(E, 256), 256, 0, stream>>>(src, dst, cur_src, cur_dst,
                                                eid_src, eid_dst, E);

  // ---- stage 1: x_out / (x_in + lattr) via CSR gather ----
  seg_mean_mlp<<<cdiv(N, 4), 256, 0, stream>>>(row_src, eid_src, edge_attr, epw,
                                               epb, xout, nullptr, N);
  seg_mean_mlp<<<cdiv(N, 4), 256, 0, stream>>>(row_dst, eid_dst, edge_attr, epw,
                                               epb, xin, lattr, N);

  // ---- stage 2: xl1/xr1 = xi @ g1wl / g1wr (xi = [xout|xin|stats], K=258) ----
  GemmA axi{xout, xin, node_stats, 128, 128, 2, 128, 256};
  {
    dim3 g(cdiv(N, 64), 4);
    gemm64<<<g, 256, 0, stream>>>(axi, g1wl, 256, xl1, 256, N, 258);
    gemm64<<<g, 256, 0, stream>>>(axi, g1wr, 256, xr1, 256, N, 258);
  }

  // ---- stage 3: GATv2 layer 1 (H=2) ----
  attn_logits<2><<<512, 256, 64 * 256 * sizeof(float), stream>>>(
      xl1, xr1, src, dst, edge_attr, lattr, g1we, g1att, lg, E, N);
  attn_fused<2><<<cdiv(N, 4), 256, 0, stream>>>(xl1, lg, row_dst, eid_dst, src,
                                                g1b, n1g, n1b, h1, E, N);

  // ---- stage 4: xl2/xr2 = h1 @ g2wl / g2wr ----
  GemmA ah1{h1, nullptr, nullptr, 128, 0, 0, 128, 128};
  {
    dim3 g(cdiv(N, 64), 2);
    gemm64<<<g, 256, 0, stream>>>(ah1, g2wl, 128, xl2, 128, N, 128);
    gemm64<<<g, 256, 0, stream>>>(ah1, g2wr, 128, xr2, 128, N, 128);
  }

  // ---- stage 5: GATv2 layer 2 (H=1) ----
  attn_logits<1><<<1024, 256, 64 * 128 * sizeof(float), stream>>>(
      xl2, xr2, src, dst, edge_attr, lattr, g2we, g2att, lg, E, N);
  attn_fused<1><<<cdiv(N, 4), 256, 0, stream>>>(xl2, lg, row_dst, eid_dst, src,
                                                g2b, n2g, n2b, h2, E, N);

  // ---- stage 6: classifier ----
  GemmA ah2{h2, nullptr, nullptr, 128, 0, 0, 128, 128};
  {
    dim3 g(cdiv(N, 64), 2);
    gemm64<<<g, 256, 0, stream>>>(ah2, c1w, 128, P, 128, N, 128);
    gemm64<<<g, 256, 0, stream>>>(ah2, c1w + 128 * 128, 128, Q, 128, N, 128);
  }
  classifier<<<1024, 256, 0, stream>>>(P, Q, src, dst, edge_attr, c1w + 256 * 128,
                                       c1b, c2w, c2b, c3w, c3b, out, E);
}

// Round 3
// 1910.992 us; speedup vs baseline: 3.3470x; 2.2115x over previous
//
#include <hip/hip_runtime.h>
#include <cstdint>
#include <cstddef>

// ---------------------------------------------------------------------------
// StaticGNN fused pipeline, fp32, round 3: tiled GEMM engine everywhere.
// N=50000 nodes, E=400000 edges, ND=128, ED=64, HID=128.
// ---------------------------------------------------------------------------

static inline int cdiv(int a, int b) { return (a + b - 1) / b; }

// ---------------------------------------------------------------------------
// CSR build
// ---------------------------------------------------------------------------
__global__ void count_deg(const int* __restrict__ src, const int* __restrict__ dst,
                          int* __restrict__ dsrc, int* __restrict__ ddst, int E) {
  int t = blockIdx.x * blockDim.x + threadIdx.x;
  if (t < E) {
    atomicAdd(&dsrc[src[t]], 1);
    atomicAdd(&ddst[dst[t]], 1);
  }
}

__global__ __launch_bounds__(1024) void scan_pair(
    const int* __restrict__ degA, const int* __restrict__ degB,
    int* __restrict__ rowA, int* __restrict__ rowB, int* __restrict__ curA,
    int* __restrict__ curB, int N) {
  __shared__ int part[1024];
  int tid = threadIdx.x;
  int chunk = (N + 1023) / 1024;
  for (int arr = 0; arr < 2; arr++) {
    const int* deg = arr ? degB : degA;
    int* row = arr ? rowB : rowA;
    int* cur = arr ? curB : curA;
    int lo = tid * chunk, hi = min(lo + chunk, N);
    int s = 0;
    for (int i = lo; i < hi; i++) s += deg[i];
    part[tid] = s;
    __syncthreads();
    for (int off = 1; off < 1024; off <<= 1) {
      int v = (tid >= off) ? part[tid - off] : 0;
      __syncthreads();
      if (tid >= off) part[tid] += v;
      __syncthreads();
    }
    int run = (tid == 0) ? 0 : part[tid - 1];
    for (int i = lo; i < hi; i++) {
      row[i] = run;
      cur[i] = run;
      run += deg[i];
    }
    if (tid == 1023) row[N] = part[1023];
    __syncthreads();
  }
}

__global__ void scatter_eid(const int* __restrict__ src, const int* __restrict__ dst,
                            int* __restrict__ csrc, int* __restrict__ cdst,
                            int* __restrict__ esrc, int* __restrict__ edst, int E) {
  int t = blockIdx.x * blockDim.x + threadIdx.x;
  if (t < E) {
    int p = atomicAdd(&csrc[src[t]], 1);
    esrc[p] = t;
    int q = atomicAdd(&cdst[dst[t]], 1);
    edst[q] = t;
  }
}

// ---------------------------------------------------------------------------
// Virtual 3-way concatenated A operand (for xi = [x_out | x_in | stats]).
// ---------------------------------------------------------------------------
struct ASrc {
  const float *p0, *p1, *p2;
  int ld0, ld1, ld2, k0, k1;
};
__device__ __forceinline__ float loadA(const ASrc& a, int m, int k) {
  if (k < a.k0) return a.p0[(size_t)m * a.ld0 + k];
  if (k < a.k1) return a.p1[(size_t)m * a.ld1 + (k - a.k0)];
  return a.p2[(size_t)m * a.ld2 + (k - a.k1)];
}
__device__ __forceinline__ int regionOf(const ASrc& a, int k) {
  return k < a.k0 ? 0 : (k < a.k1 ? 1 : 2);
}

// ---------------------------------------------------------------------------
// Generic tiled GEMM: C[M, n0..n0+128) = act(A[M,K] @ B[K, ...] + bias).
// 64-row x 128-col tile, 256 threads, 4x8 micro-tile. ACT: 0=none, 1=relu.
// A tile staged k-major with pad 68 (conflict-free b128 reads).
// ---------------------------------------------------------------------------
template <int ACT>
__global__ __launch_bounds__(256) void gemm_tiled(
    ASrc A, const float* __restrict__ B, int ldb, const float* __restrict__ bias,
    float* __restrict__ C, int ldc, int M, int K) {
  __shared__ __align__(16) float as[64 * 68];
  __shared__ __align__(16) float bs[64 * 128];
  __shared__ float bsh[128];
  int tid = threadIdx.x;
  int m0 = blockIdx.x * 64;
  int n0 = blockIdx.y * 128;
  if (tid < 128) bsh[tid] = bias ? bias[n0 + tid] : 0.f;
  int er = tid >> 4, cc = tid & 15;
  float acc[4][8] = {};
  for (int kc = 0; kc < K; kc += 64) {
    __syncthreads();
    {  // stage A chunk (k-major)
      int row = tid & 63, kq = tid >> 6;
      int gm = m0 + row;
      bool fastc = (kc + 64 <= K) && (regionOf(A, kc) == regionOf(A, kc + 63)) &&
                   (gm < M);
      if (fastc) {
        int r = regionOf(A, kc);
        const float* p;
        int ld, koff;
        if (r == 0) { p = A.p0; ld = A.ld0; koff = 0; }
        else if (r == 1) { p = A.p1; ld = A.ld1; koff = A.k0; }
        else { p = A.p2; ld = A.ld2; koff = A.k1; }
        const float* rp = p + (size_t)gm * ld + (kc - koff) + kq * 16;
#pragma unroll
        for (int q = 0; q < 4; q++) {
          float4 v = *(const float4*)(rp + q * 4);
          int kl = kq * 16 + q * 4;
          as[(kl + 0) * 68 + row] = v.x;
          as[(kl + 1) * 68 + row] = v.y;
          as[(kl + 2) * 68 + row] = v.z;
          as[(kl + 3) * 68 + row] = v.w;
        }
      } else {
#pragma unroll
        for (int q = 0; q < 16; q++) {
          int kl = kq * 16 + q;
          int kk = kc + kl;
          as[kl * 68 + row] = (gm < M && kk < K) ? loadA(A, gm, kk) : 0.f;
        }
      }
    }
    {  // stage B chunk
#pragma unroll
      for (int i = 0; i < 8; i++) {
        int idx = tid + i * 256;
        int k = idx >> 5, c4 = (idx & 31) * 4;
        int kk = kc + k;
        float4 v;
        if (kk < K) v = *(const float4*)&B[(size_t)kk * ldb + n0 + c4];
        else v = make_float4(0.f, 0.f, 0.f, 0.f);
        *(float4*)&bs[k * 128 + c4] = v;
      }
    }
    __syncthreads();
#pragma unroll 4
    for (int k = 0; k < 64; k++) {
      float4 av = *(const float4*)&as[k * 68 + er * 4];
      float4 b0 = *(const float4*)&bs[k * 128 + cc * 4];
      float4 b1 = *(const float4*)&bs[k * 128 + 64 + cc * 4];
      float aa[4] = {av.x, av.y, av.z, av.w};
      float bb[8] = {b0.x, b0.y, b0.z, b0.w, b1.x, b1.y, b1.z, b1.w};
#pragma unroll
      for (int i2 = 0; i2 < 4; i2++)
#pragma unroll
        for (int j = 0; j < 8; j++) acc[i2][j] += aa[i2] * bb[j];
    }
  }
#pragma unroll
  for (int i2 = 0; i2 < 4; i2++) {
    int row = m0 + er * 4 + i2;
    if (row >= M) continue;
#pragma unroll
    for (int h = 0; h < 2; h++) {
      int c = h * 64 + cc * 4;
      float4 v;
      v.x = acc[i2][h * 4 + 0] + bsh[c + 0];
      v.y = acc[i2][h * 4 + 1] + bsh[c + 1];
      v.z = acc[i2][h * 4 + 2] + bsh[c + 2];
      v.w = acc[i2][h * 4 + 3] + bsh[c + 3];
      if (ACT == 1) {
        v.x = fmaxf(v.x, 0.f);
        v.y = fmaxf(v.y, 0.f);
        v.z = fmaxf(v.z, 0.f);
        v.w = fmaxf(v.w, 0.f);
      }
      *(float4*)&C[(size_t)row * ldc + n0 + c] = v;
    }
  }
}

// ---------------------------------------------------------------------------
// gather-mean: side 0: x_out = mean emb over out-edges; side 1: x_in +
// lattr = mean(ea). Wave per (node, side).
// ---------------------------------------------------------------------------
__global__ __launch_bounds__(256) void gather_mean(
    const int* __restrict__ row_src, const int* __restrict__ eid_src,
    const int* __restrict__ row_dst, const int* __restrict__ eid_dst,
    const float* __restrict__ emb, const float* __restrict__ ea,
    float* __restrict__ xout, float* __restrict__ xin, float* __restrict__ lattr,
    int N) {
  int lane = threadIdx.x & 63, wid = threadIdx.x >> 6;
  int n = blockIdx.x * 4 + wid;
  int side = blockIdx.y;
  if (n >= N) return;
  const int* row = side ? row_dst : row_src;
  const int* eid = side ? eid_dst : eid_src;
  int lo = row[n], hi = row[n + 1];
  float a0 = 0.f, a1 = 0.f, la = 0.f;
  for (int j = lo; j < hi; j++) {
    int e = eid[j];
    float2 v = *(const float2*)&emb[(size_t)e * 128 + lane * 2];
    a0 += v.x;
    a1 += v.y;
    if (side) la += ea[(size_t)e * 64 + lane];
  }
  float r = 1.f / fmaxf((float)(hi - lo), 1.f);
  float* ob = side ? xin : xout;
  float2 o = make_float2(a0 * r, a1 * r);
  *(float2*)&ob[(size_t)n * 128 + lane * 2] = o;
  if (side) lattr[(size_t)n * 64 + lane] = la * r;
}

// ---------------------------------------------------------------------------
// attn_logits_tiled<H>: per 64-ext-edge tile, head slab of 128 cols:
// M = ea2 @ we ; epilogue: leaky(M + xl[s] + xr[d]) . att -> logit.
// ---------------------------------------------------------------------------
template <int H>
__global__ __launch_bounds__(256) void attn_logits_tiled(
    const float* __restrict__ xl, const float* __restrict__ xr,
    const int* __restrict__ src, const int* __restrict__ dst,
    const float* __restrict__ ea, const float* __restrict__ lattr,
    const float* __restrict__ we, const float* __restrict__ att,
    float* __restrict__ lg, int E, int N) {
  constexpr int HC = H * 128;
  __shared__ __align__(16) float as[64 * 68];
  __shared__ __align__(16) float bs[64 * 128];
  __shared__ float atts[128];
  __shared__ int sidx[64], didx[64];
  int tid = threadIdx.x;
  int E2 = E + N;
  int i0 = blockIdx.x * 64;
  int head = blockIdx.y;
  int n0 = head * 128;
  if (tid < 128) atts[tid] = att[n0 + tid];
  if (tid < 64) {
    int gi = i0 + tid;
    int s = 0, dd = 0;
    if (gi < E2) {
      if (gi < E) { s = src[gi]; dd = dst[gi]; }
      else { s = dd = gi - E; }
    }
    sidx[tid] = s;
    didx[tid] = dd;
  }
  {  // stage A (ext-edge rows, K=64)
    int row = tid & 63, kq = tid >> 6;
    int gi = i0 + row;
    if (gi < E2) {
      const float* ap = (gi < E) ? ea + (size_t)gi * 64 : lattr + (size_t)(gi - E) * 64;
      const float* rp = ap + kq * 16;
#pragma unroll
      for (int q = 0; q < 4; q++) {
        float4 v = *(const float4*)(rp + q * 4);
        int kl = kq * 16 + q * 4;
        as[(kl + 0) * 68 + row] = v.x;
        as[(kl + 1) * 68 + row] = v.y;
        as[(kl + 2) * 68 + row] = v.z;
        as[(kl + 3) * 68 + row] = v.w;
      }
    } else {
#pragma unroll
      for (int q = 0; q < 16; q++) as[(kq * 16 + q) * 68 + row] = 0.f;
    }
  }
  {  // stage we slab
#pragma unroll
    for (int i = 0; i < 8; i++) {
      int idx = tid + i * 256;
      int k = idx >> 5, c4 = (idx & 31) * 4;
      float4 v = *(const float4*)&we[(size_t)k * HC + n0 + c4];
      *(float4*)&bs[k * 128 + c4] = v;
    }
  }
  __syncthreads();
  int er = tid >> 4, cc = tid & 15;
  float acc[4][8] = {};
#pragma unroll 4
  for (int k = 0; k < 64; k++) {
    float4 av = *(const float4*)&as[k * 68 + er * 4];
    float4 b0 = *(const float4*)&bs[k * 128 + cc * 4];
    float4 b1 = *(const float4*)&bs[k * 128 + 64 + cc * 4];
    float aa[4] = {av.x, av.y, av.z, av.w};
    float bb[8] = {b0.x, b0.y, b0.z, b0.w, b1.x, b1.y, b1.z, b1.w};
#pragma unroll
    for (int i2 = 0; i2 < 4; i2++)
#pragma unroll
      for (int j = 0; j < 8; j++) acc[i2][j] += aa[i2] * bb[j];
  }
#pragma unroll
  for (int i2 = 0; i2 < 4; i2++) {
    int gi = i0 + er * 4 + i2;
    float ps = 0.f;
    if (gi < E2) {
      int s = sidx[er * 4 + i2], dd = didx[er * 4 + i2];
#pragma unroll
      for (int h = 0; h < 2; h++) {
        int c = h * 64 + cc * 4;
        float4 xlv = *(const float4*)&xl[(size_t)s * HC + n0 + c];
        float4 xrv = *(const float4*)&xr[(size_t)dd * HC + n0 + c];
        float e0 = acc[i2][h * 4 + 0] + xlv.x + xrv.x;
        float e1 = acc[i2][h * 4 + 1] + xlv.y + xrv.y;
        float e2 = acc[i2][h * 4 + 2] + xlv.z + xrv.z;
        float e3 = acc[i2][h * 4 + 3] + xlv.w + xrv.w;
        e0 = e0 > 0.f ? e0 : 0.2f * e0;
        e1 = e1 > 0.f ? e1 : 0.2f * e1;
        e2 = e2 > 0.f ? e2 : 0.2f * e2;
        e3 = e3 > 0.f ? e3 : 0.2f * e3;
        ps += e0 * atts[c + 0] + e1 * atts[c + 1] + e2 * atts[c + 2] +
              e3 * atts[c + 3];
      }
    }
    ps += __shfl_xor(ps, 1);
    ps += __shfl_xor(ps, 2);
    ps += __shfl_xor(ps, 4);
    ps += __shfl_xor(ps, 8);
    if (cc == 0 && gi < E2) lg[(size_t)gi * H + head] = ps;
  }
}

// ---------------------------------------------------------------------------
// attn_fused<H>: softmax + aggregate + head-mean + bias + LN + ELU.
// Wave per destination node (CSR gather).
// ---------------------------------------------------------------------------
template <int H>
__global__ __launch_bounds__(256) void attn_fused(
    const float* __restrict__ xl, const float* __restrict__ lg,
    const int* __restrict__ row, const int* __restrict__ eid,
    const int* __restrict__ src, const float* __restrict__ bias,
    const float* __restrict__ gam, const float* __restrict__ bet,
    float* __restrict__ hout, int E, int N) {
  constexpr int HC = H * 128;
  constexpr int CPL = HC / 64;
  int lane = threadIdx.x & 63, wid = threadIdx.x >> 6;
  int n = blockIdx.x * 4 + wid;
  if (n >= N) return;
  int lo = row[n], hi = row[n + 1];
  int myh = (H == 2) ? (lane >> 5) : 0;
  float m = lg[(size_t)(E + n) * H + myh];
  for (int j = lo; j < hi; j++) m = fmaxf(m, lg[(size_t)eid[j] * H + myh]);
  float asum = 0.f;
  float acc[CPL] = {};
  {
    float a = __expf(lg[(size_t)(E + n) * H + myh] - m);
    asum += a;
    const float* xp = &xl[(size_t)n * HC + lane * CPL];
#pragma unroll
    for (int k = 0; k < CPL; k++) acc[k] += a * xp[k];
  }
  for (int j = lo; j < hi; j++) {
    int e = eid[j];
    int s = src[e];
    float a = __expf(lg[(size_t)e * H + myh] - m);
    asum += a;
    const float* xp = &xl[(size_t)s * HC + lane * CPL];
#pragma unroll
    for (int k = 0; k < CPL; k++) acc[k] += a * xp[k];
  }
  float inv = 1.f / fmaxf(asum, 1e-16f);
#pragma unroll
  for (int k = 0; k < CPL; k++) acc[k] *= inv;
  int ch;
  if (H == 2) {
#pragma unroll
    for (int k = 0; k < CPL; k++) acc[k] = (acc[k] + __shfl_xor(acc[k], 32)) * 0.5f;
    ch = (lane & 31) * CPL;
  } else {
    ch = lane * CPL;
  }
#pragma unroll
  for (int k = 0; k < CPL; k++) acc[k] += bias[ch + k];
  float s = 0.f;
#pragma unroll
  for (int k = 0; k < CPL; k++) s += acc[k];
#pragma unroll
  for (int mm = 1; mm < 64; mm <<= 1) s += __shfl_xor(s, mm);
  constexpr float dupn = (H == 2) ? 256.f : 128.f;
  float mu = s / dupn;
  float vs = 0.f;
#pragma unroll
  for (int k = 0; k < CPL; k++) {
    acc[k] -= mu;
    vs += acc[k] * acc[k];
  }
#pragma unroll
  for (int mm = 1; mm < 64; mm <<= 1) vs += __shfl_xor(vs, mm);
  float rstd = rsqrtf(vs / dupn + 1e-5f);
  float y[CPL];
#pragma unroll
  for (int k = 0; k < CPL; k++) {
    float v = acc[k] * rstd * gam[ch + k] + bet[ch + k];
    y[k] = v > 0.f ? v : expm1f(v);
  }
  if (H == 2) {
    if (lane < 32) {
      float4 o = make_float4(y[0], y[1], y[2], y[3]);
      *(float4*)&hout[(size_t)n * 128 + ch] = o;
    }
  } else {
    float2 o = make_float2(y[0], y[1]);
    *(float2*)&hout[(size_t)n * 128 + ch] = o;
  }
}

// ---------------------------------------------------------------------------
// t1_gemm: t1[E,128] = relu(ea @ Wc + P[src] + Q[dst] + c1b)
// ---------------------------------------------------------------------------
__global__ __launch_bounds__(256) void t1_gemm(
    const float* __restrict__ ea, const float* __restrict__ Wc,
    const int* __restrict__ src, const int* __restrict__ dst,
    const float* __restrict__ P, const float* __restrict__ Q,
    const float* __restrict__ c1b, float* __restrict__ t1, int E) {
  __shared__ __align__(16) float as[64 * 68];
  __shared__ __align__(16) float bs[64 * 128];
  __shared__ float bsh[128];
  __shared__ int sidx[64], didx[64];
  int tid = threadIdx.x;
  int e0 = blockIdx.x * 64;
  if (tid < 128) bsh[tid] = c1b[tid];
  if (tid < 64) {
    int gi = e0 + tid;
    sidx[tid] = gi < E ? src[gi] : 0;
    didx[tid] = gi < E ? dst[gi] : 0;
  }
  {
    int row = tid & 63, kq = tid >> 6;
    int gi = e0 + row;
    if (gi < E) {
      const float* rp = ea + (size_t)gi * 64 + kq * 16;
#pragma unroll
      for (int q = 0; q < 4; q++) {
        float4 v = *(const float4*)(rp + q * 4);
        int kl = kq * 16 + q * 4;
        as[(kl + 0) * 68 + row] = v.x;
        as[(kl + 1) * 68 + row] = v.y;
        as[(kl + 2) * 68 + row] = v.z;
        as[(kl + 3) * 68 + row] = v.w;
      }
    } else {
#pragma unroll
      for (int q = 0; q < 16; q++) as[(kq * 16 + q) * 68 + row] = 0.f;
    }
  }
  {
#pragma unroll
    for (int i = 0; i < 8; i++) {
      int idx = tid + i * 256;
      int k = idx >> 5, c4 = (idx & 31) * 4;
      float4 v = *(const float4*)&Wc[(size_t)k * 128 + c4];
      *(float4*)&bs[k * 128 + c4] = v;
    }
  }
  __syncthreads();
  int er = tid >> 4, cc = tid & 15;
  float acc[4][8] = {};
#pragma unroll 4
  for (int k = 0; k < 64; k++) {
    float4 av = *(const float4*)&as[k * 68 + er * 4];
    float4 b0 = *(const float4*)&bs[k * 128 + cc * 4];
    float4 b1 = *(const float4*)&bs[k * 128 + 64 + cc * 4];
    float aa[4] = {av.x, av.y, av.z, av.w};
    float bb[8] = {b0.x, b0.y, b0.z, b0.w, b1.x, b1.y, b1.z, b1.w};
#pragma unroll
    for (int i2 = 0; i2 < 4; i2++)
#pragma unroll
      for (int j = 0; j < 8; j++) acc[i2][j] += aa[i2] * bb[j];
  }
#pragma unroll
  for (int i2 = 0; i2 < 4; i2++) {
    int gi = e0 + er * 4 + i2;
    if (gi >= E) continue;
    int s = sidx[er * 4 + i2], dd = didx[er * 4 + i2];
#pragma unroll
    for (int h = 0; h < 2; h++) {
      int c = h * 64 + cc * 4;
      float4 pv = *(const float4*)&P[(size_t)s * 128 + c];
      float4 qv = *(const float4*)&Q[(size_t)dd * 128 + c];
      float4 v;
      v.x = fmaxf(acc[i2][h * 4 + 0] + pv.x + qv.x + bsh[c + 0], 0.f);
      v.y = fmaxf(acc[i2][h * 4 + 1] + pv.y + qv.y + bsh[c + 1], 0.f);
      v.z = fmaxf(acc[i2][h * 4 + 2] + pv.z + qv.z + bsh[c + 2], 0.f);
      v.w = fmaxf(acc[i2][h * 4 + 3] + pv.w + qv.w + bsh[c + 3], 0.f);
      *(float4*)&t1[(size_t)gi * 128 + c] = v;
    }
  }
}

// ---------------------------------------------------------------------------
// t2out_gemm: out[E] = relu(t1 @ c2w + c2b) . c3w + c3b
// ---------------------------------------------------------------------------
__global__ __launch_bounds__(256) void t2out_gemm(
    const float* __restrict__ t1, const float* __restrict__ c2w,
    const float* __restrict__ c2b, const float* __restrict__ c3w,
    const float* __restrict__ c3b, float* __restrict__ out, int E) {
  __shared__ __align__(16) float as[64 * 68];
  __shared__ __align__(16) float bs[64 * 64];
  __shared__ float c2bs[64], c3ws[64];
  int tid = threadIdx.x;
  int e0 = blockIdx.x * 64;
  if (tid < 64) {
    c2bs[tid] = c2b[tid];
    c3ws[tid] = c3w[tid];
  }
  int er = tid >> 4, cc = tid & 15;
  float acc[4][4] = {};
  for (int kc = 0; kc < 128; kc += 64) {
    __syncthreads();
    {
      int row = tid & 63, kq = tid >> 6;
      int gi = e0 + row;
      if (gi < E) {
        const float* rp = t1 + (size_t)gi * 128 + kc + kq * 16;
#pragma unroll
        for (int q = 0; q < 4; q++) {
          float4 v = *(const float4*)(rp + q * 4);
          int kl = kq * 16 + q * 4;
          as[(kl + 0) * 68 + row] = v.x;
          as[(kl + 1) * 68 + row] = v.y;
          as[(kl + 2) * 68 + row] = v.z;
          as[(kl + 3) * 68 + row] = v.w;
        }
      } else {
#pragma unroll
        for (int q = 0; q < 16; q++) as[(kq * 16 + q) * 68 + row] = 0.f;
      }
    }
    {
#pragma unroll
      for (int i = 0; i < 4; i++) {
        int idx = tid + i * 256;
        int k = idx >> 4, c4 = (idx & 15) * 4;
        float4 v = *(const float4*)&c2w[(size_t)(kc + k) * 64 + c4];
        *(float4*)&bs[k * 64 + c4] = v;
      }
    }
    __syncthreads();
#pragma unroll 4
    for (int k = 0; k < 64; k++) {
      float4 av = *(const float4*)&as[k * 68 + er * 4];
      float4 bv = *(const float4*)&bs[k * 64 + cc * 4];
      float aa[4] = {av.x, av.y, av.z, av.w};
      float bb[4] = {bv.x, bv.y, bv.z, bv.w};
#pragma unroll
      for (int i2 = 0; i2 < 4; i2++)
#pragma unroll
        for (int j = 0; j < 4; j++) acc[i2][j] += aa[i2] * bb[j];
    }
  }
  float c3b0 = c3b[0];
#pragma unroll
  for (int i2 = 0; i2 < 4; i2++) {
    int gi = e0 + er * 4 + i2;
    float ps = 0.f;
#pragma unroll
    for (int t = 0; t < 4; t++) {
      float t2v = fmaxf(acc[i2][t] + c2bs[cc * 4 + t], 0.f);
      ps += t2v * c3ws[cc * 4 + t];
    }
    ps += __shfl_xor(ps, 1);
    ps += __shfl_xor(ps, 2);
    ps += __shfl_xor(ps, 4);
    ps += __shfl_xor(ps, 8);
    if (cc == 0 && gi < E) out[gi] = ps + c3b0;
  }
}

// ---------------------------------------------------------------------------
extern "C" void kernel_launch(void* const* d_in, const int* in_sizes, int n_in,
                              void* d_out, int out_size, void* d_ws, size_t ws_size,
                              hipStream_t stream) {
  const int N = in_sizes[1] / 2;   // node_stats [N,2]
  const int E = in_sizes[3] / 64;  // edge_attr [E,64]

  const float* node_stats = (const float*)d_in[1];
  const int* src = (const int*)d_in[2];
  const int* dst = (const int*)d_in[2] + E;
  const float* edge_attr = (const float*)d_in[3];
  const float* epw = (const float*)d_in[4];
  const float* epb = (const float*)d_in[5];
  const float* g1wl = (const float*)d_in[6];
  const float* g1wr = (const float*)d_in[7];
  const float* g1we = (const float*)d_in[8];
  const float* g1att = (const float*)d_in[9];
  const float* g1b = (const float*)d_in[10];
  const float* n1g = (const float*)d_in[11];
  const float* n1b = (const float*)d_in[12];
  const float* g2wl = (const float*)d_in[13];
  const float* g2wr = (const float*)d_in[14];
  const float* g2we = (const float*)d_in[15];
  const float* g2att = (const float*)d_in[16];
  const float* g2b = (const float*)d_in[17];
  const float* n2g = (const float*)d_in[18];
  const float* n2b = (const float*)d_in[19];
  const float* c1w = (const float*)d_in[20];
  const float* c1b = (const float*)d_in[21];
  const float* c2w = (const float*)d_in[22];
  const float* c2b = (const float*)d_in[23];
  const float* c3w = (const float*)d_in[24];
  const float* c3b = (const float*)d_in[25];
  float* out = (float*)d_out;

  // workspace arena
  float* w = (float*)d_ws;
  size_t o = 0;
  auto alloc = [&](size_t n) { float* p = w + o; o += n; return p; };
  float* xout = alloc((size_t)N * 128);    // later: xl2, then P
  float* xin = alloc((size_t)N * 128);     // later: xr2, then Q
  float* lattr = alloc((size_t)N * 64);
  float* lg = alloc((size_t)(E + N) * 2);
  int* row_src = (int*)alloc((size_t)(N + 1));
  int* row_dst = (int*)alloc((size_t)(N + 1));
  int* deg_src = (int*)alloc((size_t)N);   // deg_src/deg_dst contiguous (memset)
  int* deg_dst = (int*)alloc((size_t)N);
  int* cur_src = (int*)alloc((size_t)N);
  int* cur_dst = (int*)alloc((size_t)N);
  int* eid_src = (int*)alloc((size_t)E);
  int* eid_dst = (int*)alloc((size_t)E);
  float* R = alloc((size_t)E * 128);       // emb -> (xl1|xr1) -> t1
  float* emb = R;
  float* xl1 = R;
  float* xr1 = R + (size_t)N * 256;
  float* h1 = xr1;
  float* xl2 = xout;
  float* xr2 = xin;
  float* h2 = xl1;
  float* P = xout;
  float* Q = xin;
  float* t1 = R;

  // ---- stage 0: CSR ----
  hipMemsetAsync(deg_src, 0, (size_t)2 * N * sizeof(int), stream);
  count_deg<<<cdiv(E, 256), 256, 0, stream>>>(src, dst, deg_src, deg_dst, E);
  scan_pair<<<1, 1024, 0, stream>>>(deg_src, deg_dst, row_src, row_dst, cur_src,
                                    cur_dst, N);
  scatter_eid<<<cdiv(E, 256), 256, 0, stream>>>(src, dst, cur_src, cur_dst,
                                                eid_src, eid_dst, E);

  // ---- stage 1: emb = relu(ea@epw+epb); gather means ----
  {
    ASrc a{edge_attr, nullptr, nullptr, 64, 0, 0, 64, 64};
    dim3 g(cdiv(E, 64), 1);
    gemm_tiled<1><<<g, 256, 0, stream>>>(a, epw, 128, epb, emb, 128, E, 64);
  }
  {
    dim3 g(cdiv(N, 4), 2);
    gather_mean<<<g, 256, 0, stream>>>(row_src, eid_src, row_dst, eid_dst, emb,
                                       edge_attr, xout, xin, lattr, N);
  }

  // ---- stage 2: xl1/xr1 = xi @ g1wl / g1wr  (K=258, Nc=256) ----
  {
    ASrc a{xout, xin, node_stats, 128, 128, 2, 128, 256};
    dim3 g(cdiv(N, 64), 2);
    gemm_tiled<0><<<g, 256, 0, stream>>>(a, g1wl, 256, nullptr, xl1, 256, N, 258);
    gemm_tiled<0><<<g, 256, 0, stream>>>(a, g1wr, 256, nullptr, xr1, 256, N, 258);
  }

  // ---- stage 3: GATv2 layer 1 (H=2) ----
  {
    dim3 g(cdiv(E + N, 64), 2);
    attn_logits_tiled<2><<<g, 256, 0, stream>>>(xl1, xr1, src, dst, edge_attr,
                                                lattr, g1we, g1att, lg, E, N);
  }
  attn_fused<2><<<cdiv(N, 4), 256, 0, stream>>>(xl1, lg, row_dst, eid_dst, src,
                                                g1b, n1g, n1b, h1, E, N);

  // ---- stage 4: xl2/xr2 = h1 @ g2wl / g2wr ----
  {
    ASrc a{h1, nullptr, nullptr, 128, 0, 0, 128, 128};
    dim3 g(cdiv(N, 64), 1);
    gemm_tiled<0><<<g, 256, 0, stream>>>(a, g2wl, 128, nullptr, xl2, 128, N, 128);
    gemm_tiled<0><<<g, 256, 0, stream>>>(a, g2wr, 128, nullptr, xr2, 128, N, 128);
  }

  // ---- stage 5: GATv2 layer 2 (H=1) ----
  {
    dim3 g(cdiv(E + N, 64), 1);
    attn_logits_tiled<1><<<g, 256, 0, stream>>>(xl2, xr2, src, dst, edge_attr,
                                                lattr, g2we, g2att, lg, E, N);
  }
  attn_fused<1><<<cdiv(N, 4), 256, 0, stream>>>(xl2, lg, row_dst, eid_dst, src,
                                                g2b, n2g, n2b, h2, E, N);

  // ---- stage 6: classifier ----
  {
    ASrc a{h2, nullptr, nullptr, 128, 0, 0, 128, 128};
    dim3 g(cdiv(N, 64), 1);
    gemm_tiled<0><<<g, 256, 0, stream>>>(a, c1w, 128, nullptr, P, 128, N, 128);
    gemm_tiled<0><<<g, 256, 0, stream>>>(a, c1w + 128 * 128, 128, nullptr, Q, 128,
                                         N, 128);
  }
  t1_gemm<<<cdiv(E, 64), 256, 0, stream>>>(edge_attr, c1w + 256 * 128, src, dst, P,
                                           Q, c1b, t1, E);
  t2out_gemm<<<cdiv(E, 64), 256, 0, stream>>>(t1, c2w, c2b, c3w, c3b, out, E);
}